// Round 16
// baseline (174.361 us; speedup 1.0000x reference)
//
#include <hip/hip_runtime.h>
#include <math.h>

#define NQ 12
#define NL 4
#define NA 6
#define BATCH 4096
#define NT 256
#define NBLK (BATCH / 2)   // 2 batch elements per block
#define RSTR 17            // f2 row stride (R15-verified b64 transpose mechanics)

typedef float f2 __attribute__((ext_vector_type(2)));
typedef float f4 __attribute__((ext_vector_type(4)));
typedef __fp16 v4h __attribute__((ext_vector_type(4)));
typedef __fp16 h2v __attribute__((ext_vector_type(2)));

#define WFENCE() asm volatile("s_waitcnt lgkmcnt(0)" ::: "memory")

union HF2 { v4h h; f2 f; unsigned int u[2]; };

__device__ __forceinline__ v4h pk4(f4 v) {
    union { h2v h[2]; v4h v4; } u;
    u.h[0] = __builtin_amdgcn_cvt_pkrtz(v.x, v.y);
    u.h[1] = __builtin_amdgcn_cvt_pkrtz(v.z, v.w);
    return u.v4;
}
__device__ __forceinline__ float pkamp(float re, float im) {
    union { h2v h; float f; } u;
    u.h = __builtin_amdgcn_cvt_pkrtz(re, im);
    return u.f;
}
__device__ __forceinline__ f4 gmm(v4h a, v4h b) {
    return __builtin_amdgcn_mfma_f32_16x16x16f16(a, b, (f4){0.f, 0.f, 0.f, 0.f}, 0, 0, 0);
}
// assemble a v4h frag (4 f16 over i) from 4 amp dwords (re lo-half, im hi-half)
__device__ __forceinline__ void frag_from_amps(const unsigned int* a, v4h* fre, v4h* fim) {
    union { unsigned int u[2]; v4h h; } ur, ui;
    ur.u[0] = __builtin_amdgcn_perm(a[1], a[0], 0x05040100u);
    ur.u[1] = __builtin_amdgcn_perm(a[3], a[2], 0x05040100u);
    ui.u[0] = __builtin_amdgcn_perm(a[1], a[0], 0x07060302u);
    ui.u[1] = __builtin_amdgcn_perm(a[3], a[2], 0x07060302u);
    *fre = ur.h; *fim = ui.h;
}

// ===== Layouts (amp bit b11..b0; wire q <-> bit 11-q; lane l5..l0, wave w1w0, reg (c<<2)|i) =====
// M1: b11..b8 = (l5,l4,i1,i0) [K-pos], b7..b4 = (l3,l2,l1,l0) [N], b3..b0 = (c1,c0,w1,w0)
// M2: b11..b8 = (l3,l2,l1,l0), b7..b4 = (l5,l4,i1,i0), b3..b0 = (c1,c0,w1,w0)
// M3: b11..b8 = (l3,l2,l1,l0), b7..b4 = (c1,c0,w1,w0), b3..b0 = (l5,l4,i1,i0)
// T1 (M1<->M2, involution, wave-local): read row (w<<6)|(l3,l2,l5,l4,i'), slot c'*4+(lam&3).
//   [verified: thread(lam=0,w=1,c=2,i=3) <-> thread(lam=3,w=1) amp(c=2,i=0), amp 0x039 both sides]
// T2 (M2<->M3, involution, cross-wave): read row (i'<<6)|(c'<<4)|(lam&15), slot ((lam>>4)<<2)|w.
//   [verified: thread(lam=0b101010,w=2,c=1,i=2) <-> thread(lam=26,w=2) amp(c=2,i=2), amp 0xA6A]
// MFMA 16x16x16_f16: A[m=lane&15][k=(lane>>4)*4+i]; B[k=(lane>>4)*4+i][n=lane&15];
// D[m=(lane>>4)*4+i][n=lane&15] -> k and m share coordinates: stages chain in-register.
// Stage s = l*3+g contracts wires {4g..4g+3}, k-bit3 <-> wire 4g (highest K-pos bit).
// d_ws layout (f32): af [0,1536) (s*64+lane)*2 = v4h G-frag; al [1536,1584) alphas[4][12];
//                    dg [1584,1712) dreg[4][16] f2 (rows 0,2: M1 reg wires {2,3,8,9}; 1,3: M3 {4,5,10,11})

__global__ void setup_kernel(const float* __restrict__ weights, float* __restrict__ ws) {
    const int t = threadIdx.x;   // 64 threads
    // G-matrix A-fragments for all 12 stages
    for (int l = 0; l < NL; ++l) {
        for (int g = 0; g < 3; ++g) {
            const int s = l * 3 + g;
            const int m = t & 15, kb = (t >> 4) * 4;
            float v[4];
            for (int i = 0; i < 4; ++i) {
                const int k = kb + i;
                float prod = 1.0f;
                for (int tt = 0; tt < 4; ++tt) {
                    const int q = g * 4 + tt;
                    const float th = 0.5f * weights[(l * NQ + q) * 3 + 1];
                    const float cs = cosf(th), sn = sinf(th);
                    const int mb = (m >> (3 - tt)) & 1, kbit = (k >> (3 - tt)) & 1;
                    prod *= (mb == 0) ? (kbit == 0 ? cs : -sn) : (kbit == 0 ? sn : cs);
                }
                v[i] = prod;
            }
            union { h2v h[2]; f2 f; } u;
            u.h[0] = __builtin_amdgcn_cvt_pkrtz(v[0], v[1]);
            u.h[1] = __builtin_amdgcn_cvt_pkrtz(v[2], v[3]);
            *(f2*)(ws + (s * 64 + t) * 2) = u.f;
        }
    }
    // alphas
    if (t < 48) {
        const int d = t / NQ, q = t % NQ;
        ws[1536 + t] = (d == 0) ? 0.5f * weights[q * 3 + 0]
                                : 0.5f * (weights[((d - 1) * NQ + q) * 3 + 2] +
                                          weights[(d * NQ + q) * 3 + 0]);
    }
    // dreg tables (recompute alphas locally; no cross-thread dependency)
    {
        const int d = t >> 4, r = t & 15;
        const int c1 = (r >> 3) & 1, c0 = (r >> 2) & 1, i1 = (r >> 1) & 1, i0 = r & 1;
        auto alpha = [&](int dd, int qq) {
            return (dd == 0) ? 0.5f * weights[qq * 3 + 0]
                             : 0.5f * (weights[((dd - 1) * NQ + qq) * 3 + 2] +
                                       weights[(dd * NQ + qq) * 3 + 0]);
        };
        float gsum;
        if (d == 0 || d == 2)   // M1 reg wires {2,3,8,9} <-> bits (i1,i0,c1,c0)
            gsum = (i1 ? 1.f : -1.f) * alpha(d, 2) + (i0 ? 1.f : -1.f) * alpha(d, 3)
                 + (c1 ? 1.f : -1.f) * alpha(d, 8) + (c0 ? 1.f : -1.f) * alpha(d, 9);
        else                     // M3 reg wires {4,5,10,11} <-> bits (c1,c0,i1,i0)
            gsum = (c1 ? 1.f : -1.f) * alpha(d, 4) + (c0 ? 1.f : -1.f) * alpha(d, 5)
                 + (i1 ? 1.f : -1.f) * alpha(d, 10) + (i0 ? 1.f : -1.f) * alpha(d, 11);
        float sg, cg;
        sincosf(gsum, &sg, &cg);
        ws[1584 + (d * 16 + r) * 2 + 0] = cg;
        ws[1584 + (d * 16 + r) * 2 + 1] = sg;
    }
}

__global__ __launch_bounds__(NT) void qdqn_kernel(
    const float* __restrict__ x,       // [BATCH,12]
    const float* __restrict__ ws,      // tables from setup_kernel
    const float* __restrict__ fc_w,    // [6,12]
    const float* __restrict__ fc_b,    // [6]
    float* __restrict__ out)           // [BATCH,6]
{
    __shared__ __align__(16) f2 buf[NT * RSTR];   // 34816 B; .x = elem A amp dword, .y = elem B
    __shared__ float encc[2][NQ], encs[2][NQ];
    __shared__ float redA[4][NQ], redB[4][NQ];
    __shared__ float qoutA[NQ], qoutB[NQ];

    const int tix = threadIdx.x;
    const int lam = tix & 63;
    const int w   = tix >> 6;
    const int w1  = (w >> 1) & 1, w0 = w & 1;
    const int l5 = (lam >> 5) & 1, l4 = (lam >> 4) & 1, l3 = (lam >> 3) & 1;
    const int l2 = (lam >> 2) & 1, l1 = (lam >> 1) & 1, l0 = lam & 1;
    const int b0 = blockIdx.x * 2;

    const float* afp = ws;
    const float* al  = ws + 1536;
    const float* dgt = ws + 1584;

    if (tix < 2 * NQ) {
        const int s = tix / NQ, q = tix % NQ;
        float sn, cs;
        sincosf(0.5f * x[(b0 + s) * NQ + q], &sn, &cs);
        encc[s][q] = cs; encs[s][q] = sn;
    }
    __syncthreads();

#define SG(bit, a) ((bit) ? (a) : -(a))
#define BETA_M1(alp) ( SG(l5,(alp)[0]) + SG(l4,(alp)[1]) + SG(l3,(alp)[4]) + SG(l2,(alp)[5]) \
                     + SG(l1,(alp)[6]) + SG(l0,(alp)[7]) + SG(w1,(alp)[10]) + SG(w0,(alp)[11]) )
#define BETA_M3(alp) ( SG(l3,(alp)[0]) + SG(l2,(alp)[1]) + SG(l1,(alp)[2]) + SG(l0,(alp)[3]) \
                     + SG(w1,(alp)[6]) + SG(w0,(alp)[7]) + SG(l5,(alp)[8]) + SG(l4,(alp)[9]) )

    // --- state frags: per c-block, per elem, per comp: v4h over i ---
    v4h Are[4], Aim[4], Bre[4], Bim[4];
    f2 tw[16];

    // --- init: RY product state in M1 + folded RZ(phi_0) diagonal ---
    {
        const float preA = SG(1, 1.0f)
            * (l5 ? encs[0][0] : encc[0][0]) * (l4 ? encs[0][1] : encc[0][1])
            * (l3 ? encs[0][4] : encc[0][4]) * (l2 ? encs[0][5] : encc[0][5])
            * (l1 ? encs[0][6] : encc[0][6]) * (l0 ? encs[0][7] : encc[0][7])
            * (w1 ? encs[0][10] : encc[0][10]) * (w0 ? encs[0][11] : encc[0][11]);
        const float preB =
              (l5 ? encs[1][0] : encc[1][0]) * (l4 ? encs[1][1] : encc[1][1])
            * (l3 ? encs[1][4] : encc[1][4]) * (l2 ? encs[1][5] : encc[1][5])
            * (l1 ? encs[1][6] : encc[1][6]) * (l0 ? encs[1][7] : encc[1][7])
            * (w1 ? encs[1][10] : encc[1][10]) * (w0 ? encs[1][11] : encc[1][11]);
        float sb, cb;
        const float beta = BETA_M1(al);
        sincosf(beta, &sb, &cb);
#pragma unroll
        for (int c = 0; c < 4; ++c) {
            f4 rea, ima, reb, imb;
#pragma unroll
            for (int i = 0; i < 4; ++i) {
                const int r = c * 4 + i;
                const f2 tab = *(const f2*)(dgt + r * 2);
                const float phx = cb * tab.x - sb * tab.y;
                const float phy = cb * tab.y + sb * tab.x;
                const float fA = (i & 2 ? encs[0][2] : encc[0][2]) * (i & 1 ? encs[0][3] : encc[0][3])
                               * (c & 2 ? encs[0][8] : encc[0][8]) * (c & 1 ? encs[0][9] : encc[0][9]);
                const float fB = (i & 2 ? encs[1][2] : encc[1][2]) * (i & 1 ? encs[1][3] : encc[1][3])
                               * (c & 2 ? encs[1][8] : encc[1][8]) * (c & 1 ? encs[1][9] : encc[1][9]);
                const float vA = preA * fA, vB = preB * fB;
                rea[i] = vA * phx; ima[i] = vA * phy;
                reb[i] = vB * phx; imb[i] = vB * phy;
            }
            Are[c] = pk4(rea); Aim[c] = pk4(ima); Bre[c] = pk4(reb); Bim[c] = pk4(imb);
        }
    }

    const int col2   = ((lam >> 4) << 2) | w;                       // T2 read slot (fixed)
    const int t1base = (((lam >> 2) & 3) << 4) | (((lam >> 4) & 3) << 2);  // T1 src-lane base

#define LOAD_AF(sidx) { HF2 _u; _u.f = *(const f2*)(afp + ((sidx) * 64 + lam) * 2); af = _u.h; }

#define STAGE_TRANS(sidx) do { \
    v4h af; LOAD_AF(sidx); \
    _Pragma("unroll") for (int c = 0; c < 4; ++c) { \
        f4 ra = gmm(af, Are[c]), ia = gmm(af, Aim[c]); \
        f4 rb = gmm(af, Bre[c]), ib = gmm(af, Bim[c]); \
        _Pragma("unroll") for (int i = 0; i < 4; ++i) \
            tw[c * 4 + i] = (f2){ pkamp(ra[i], ia[i]), pkamp(rb[i], ib[i]) }; \
    } } while (0)

#define TW_WRITE() { _Pragma("unroll") for (int s = 0; s < 16; ++s) buf[tix * RSTR + s] = tw[s]; }

#define T1_READ() do { \
    _Pragma("unroll") for (int c = 0; c < 4; ++c) { \
        unsigned int ax[4], bx[4]; \
        _Pragma("unroll") for (int i = 0; i < 4; ++i) { \
            HF2 v; v.f = buf[((w << 6) | (t1base | i)) * RSTR + c * 4 + (lam & 3)]; \
            ax[i] = v.u[0]; bx[i] = v.u[1]; \
        } \
        frag_from_amps(ax, &Are[c], &Aim[c]); \
        frag_from_amps(bx, &Bre[c], &Bim[c]); \
    } } while (0)

#define T2_READ() do { \
    _Pragma("unroll") for (int c = 0; c < 4; ++c) { \
        unsigned int ax[4], bx[4]; \
        _Pragma("unroll") for (int i = 0; i < 4; ++i) { \
            HF2 v; v.f = buf[((i << 6) | (c << 4) | (lam & 15)) * RSTR + col2]; \
            ax[i] = v.u[0]; bx[i] = v.u[1]; \
        } \
        frag_from_amps(ax, &Are[c], &Aim[c]); \
        frag_from_amps(bx, &Bre[c], &Bim[c]); \
    } } while (0)

// diag stage: MFMA then CZ*RZ diagonal on f32 D, then repack frags
#define STAGE_DIAG(sidx, drow, isM3) do { \
    v4h af; LOAD_AF(sidx); \
    const float* alp = al + (drow) * NQ; \
    const float beta = (isM3) ? (BETA_M3(alp)) : (BETA_M1(alp)); \
    float sb, cb; sincosf(beta, &sb, &cb); \
    float basef, fI1, fI0, fC1, fC0; \
    if (isM3) { \
        const int par = (l3 & l2) + (l2 & l1) + (l1 & l0) + (w1 & w0) + (l5 & l4) + (w0 & l5); \
        basef = (par & 1) ? -1.f : 1.f; \
        fC1 = l0 ? -1.f : 1.f; fC0 = w1 ? -1.f : 1.f; fI1 = l4 ? -1.f : 1.f; fI0 = 1.f; \
    } else { \
        const int par = (l5 & l4) + (l3 & l2) + (l2 & l1) + (l1 & l0) + (w1 & w0); \
        basef = (par & 1) ? -1.f : 1.f; \
        fI1 = l4 ? -1.f : 1.f; fI0 = l3 ? -1.f : 1.f; fC1 = l0 ? -1.f : 1.f; fC0 = w1 ? -1.f : 1.f; \
    } \
    _Pragma("unroll") for (int c = 0; c < 4; ++c) { \
        f4 ra = gmm(af, Are[c]), ia = gmm(af, Aim[c]); \
        f4 rb = gmm(af, Bre[c]), ib = gmm(af, Bim[c]); \
        f4 nra, nia, nrb, nib; \
        _Pragma("unroll") for (int i = 0; i < 4; ++i) { \
            const int r = c * 4 + i; \
            const f2 tab = *(const f2*)(dgt + ((drow) * 16 + r) * 2); \
            float phx = cb * tab.x - sb * tab.y; \
            float phy = cb * tab.y + sb * tab.x; \
            float sgn = basef; \
            if (c & 2) sgn *= fC1; \
            if (c & 1) sgn *= fC0; \
            if (i & 2) sgn *= fI1; \
            if (i & 1) sgn *= fI0; \
            if (((c == 3) ? 1 : 0) ^ ((i == 3) ? 1 : 0)) sgn = -sgn; \
            phx *= sgn; phy *= sgn; \
            nra[i] = phx * ra[i] - phy * ia[i]; nia[i] = phy * ra[i] + phx * ia[i]; \
            nrb[i] = phx * rb[i] - phy * ib[i]; nib[i] = phy * rb[i] + phx * ib[i]; \
        } \
        Are[c] = pk4(nra); Aim[c] = pk4(nia); Bre[c] = pk4(nrb); Bim[c] = pk4(nib); \
    } } while (0)

    float totA = 0.f, mA2 = 0.f, mA3 = 0.f, mA8 = 0.f, mA9 = 0.f;
    float totB = 0.f, mB2 = 0.f, mB3 = 0.f, mB8 = 0.f, mB9 = 0.f;

#pragma unroll 1
    for (int h = 0; h < 2; ++h) {
        const int s0 = 6 * h;
        // ===== forward layer l=2h: M1 -> M2 -> M3 =====
        STAGE_TRANS(s0 + 0);
        WFENCE(); TW_WRITE(); WFENCE(); T1_READ();                 // T1 (wave-local)
        STAGE_TRANS(s0 + 1);
        WFENCE(); TW_WRITE(); __syncthreads(); T2_READ();          // T2 fwd (cross-wave)
        STAGE_DIAG(s0 + 2, 2 * h + 1, 1);                          // CZ + RZ in M3
        // ===== reverse layer l=2h+1: M3 -> M2 -> M1 =====
        STAGE_TRANS(s0 + 5);
        __syncthreads(); TW_WRITE(); __syncthreads(); T2_READ();   // T2 back (prior readers cross-wave)
        STAGE_TRANS(s0 + 4);
        __syncthreads(); TW_WRITE(); WFENCE(); T1_READ();          // T1 back
        if (h == 0) {
            STAGE_DIAG(s0 + 3, 2, 0);                              // CZ + RZ in M1
        } else {
            // final stage (M1) + measurement from f32 D (trailing diagonals dropped)
            v4h af; LOAD_AF(s0 + 3);
#pragma unroll
            for (int c = 0; c < 4; ++c) {
                f4 ra = gmm(af, Are[c]), ia = gmm(af, Aim[c]);
                f4 rb = gmm(af, Bre[c]), ib = gmm(af, Bim[c]);
#pragma unroll
                for (int i = 0; i < 4; ++i) {
                    const float pAv = ra[i] * ra[i] + ia[i] * ia[i];
                    const float pBv = rb[i] * rb[i] + ib[i] * ib[i];
                    totA += pAv; totB += pBv;
                    mA2 += (i & 2) ? -pAv : pAv;  mB2 += (i & 2) ? -pBv : pBv;
                    mA3 += (i & 1) ? -pAv : pAv;  mB3 += (i & 1) ? -pBv : pBv;
                    mA8 += (c & 2) ? -pAv : pAv;  mB8 += (c & 2) ? -pBv : pBv;
                    mA9 += (c & 1) ? -pAv : pAv;  mB9 += (c & 1) ? -pBv : pBv;
                }
            }
        }
    }

    // --- Z-expectations in M1: wires 0,1=l5,l4; 2,3=reg i; 4..7=l3..l0; 8,9=reg c; 10,11=w ---
    float pA[NQ], pB[NQ];
    pA[0] = l5 ? -totA : totA;  pB[0] = l5 ? -totB : totB;
    pA[1] = l4 ? -totA : totA;  pB[1] = l4 ? -totB : totB;
    pA[2] = mA2;  pB[2] = mB2;
    pA[3] = mA3;  pB[3] = mB3;
    pA[4] = l3 ? -totA : totA;  pB[4] = l3 ? -totB : totB;
    pA[5] = l2 ? -totA : totA;  pB[5] = l2 ? -totB : totB;
    pA[6] = l1 ? -totA : totA;  pB[6] = l1 ? -totB : totB;
    pA[7] = l0 ? -totA : totA;  pB[7] = l0 ? -totB : totB;
    pA[8] = mA8;  pB[8] = mB8;
    pA[9] = mA9;  pB[9] = mB9;
    pA[10] = w1 ? -totA : totA; pB[10] = w1 ? -totB : totB;
    pA[11] = w0 ? -totA : totA; pB[11] = w0 ? -totB : totB;

#pragma unroll
    for (int off = 32; off > 0; off >>= 1) {
#pragma unroll
        for (int q = 0; q < NQ; ++q) {
            pA[q] += __shfl_down(pA[q], off, 64);
            pB[q] += __shfl_down(pB[q], off, 64);
        }
    }
    if (lam == 0) {
#pragma unroll
        for (int q = 0; q < NQ; ++q) { redA[w][q] = pA[q]; redB[w][q] = pB[q]; }
    }
    __syncthreads();
    if (tix < NQ) {
        qoutA[tix] = redA[0][tix] + redA[1][tix] + redA[2][tix] + redA[3][tix];
        qoutB[tix] = redB[0][tix] + redB[1][tix] + redB[2][tix] + redB[3][tix];
    }
    __syncthreads();

    if (tix < NA) {
        float accA = fc_b[tix], accB = accA;
#pragma unroll
        for (int q = 0; q < NQ; ++q) {
            const float f = fc_w[tix * NQ + q];
            accA += qoutA[q] * f;
            accB += qoutB[q] * f;
        }
        out[b0 * NA + tix] = accA;
        out[(b0 + 1) * NA + tix] = accB;
    }
}

extern "C" void kernel_launch(void* const* d_in, const int* in_sizes, int n_in,
                              void* d_out, int out_size, void* d_ws, size_t ws_size,
                              hipStream_t stream) {
    const float* x   = (const float*)d_in[0];
    const float* wts = (const float*)d_in[1];
    const float* fcw = (const float*)d_in[2];
    const float* fcb = (const float*)d_in[3];
    float* tabs = (float*)d_ws;   // 1712 f32 = 6848 B
    setup_kernel<<<1, 64, 0, stream>>>(wts, tabs);
    qdqn_kernel<<<NBLK, NT, 0, stream>>>(x, tabs, fcw, fcb, (float*)d_out);
}